// Round 15
// baseline (150.953 us; speedup 1.0000x reference)
//
#include <hip/hip_runtime.h>
#include <hip/hip_bf16.h>
#include <stdint.h>

typedef __attribute__((ext_vector_type(8))) short bf16x8;
typedef __attribute__((ext_vector_type(4))) float f32x4;

#define DIN 1024
#define NROWS 8192

__device__ __forceinline__ unsigned short f2bf(float f) {
    union { float f; unsigned u; } v; v.f = f;
    unsigned r = v.u + 0x7FFFu + ((v.u >> 16) & 1u);  // RNE
    return (unsigned short)(r >> 16);
}

__device__ __forceinline__ int fswz(int r) { return (r ^ (r >> 2)) & 3; }

// byte offset of bf16 element (R,c) in row-major [*,1024] stored with 16B-chunk
// XOR swizzle (chunk ^= fswz(R)) within 64B groups
__device__ __forceinline__ size_t swz_byte(int R, int c) {
    return ((size_t)R * DIN + (size_t)(c & ~31)) * 2
         + (size_t)((((c >> 3) & 3) ^ fswz(R)) << 4)
         + (size_t)((c & 7) * 2);
}

__device__ __forceinline__ void gload_lds16(const void* g, void* l) {
    __builtin_amdgcn_global_load_lds(
        (const __attribute__((address_space(1))) unsigned*)g,
        (__attribute__((address_space(3))) unsigned*)l, 16, 0, 0);
}

// ---- Kernel A: vab/vag/c + cast Wab,Wag -> bf16 (fswz4) ----
__global__ __launch_bounds__(256) void prep_kernel(const float* __restrict__ Wab,
                                                   const float* __restrict__ Wag,
                                                   const float* __restrict__ bab,
                                                   const float* __restrict__ bag,
                                                   float* __restrict__ ws_f,
                                                   unsigned short* __restrict__ Whab,
                                                   unsigned short* __restrict__ Whag) {
    int b = blockIdx.x;
    int wave = threadIdx.x >> 6, lane = threadIdx.x & 63;
    if (b == 256) {
        if (wave == 0) {
            float acc = 0.f;
            for (int j = lane; j < DIN; j += 64) acc += bab[j] * bag[j];
            for (int off = 32; off; off >>= 1) acc += __shfl_xor(acc, off);
            if (lane == 0) ws_f[2048] = acc;
        }
        return;
    }
    int r = b * 4 + wave;
    int fr = fswz(r);
    {
        const float* wrow = Wab + (size_t)r * DIN;
        char* hrow = (char*)Whab + (size_t)r * DIN * 2;
        float acc = 0.f;
#pragma unroll
        for (int it = 0; it < 4; ++it) {
            int col = it * 256 + lane * 4;
            float4 w = *reinterpret_cast<const float4*>(wrow + col);
            float4 bv = *reinterpret_cast<const float4*>(bag + col);
            acc += w.x * bv.x + w.y * bv.y + w.z * bv.z + w.w * bv.w;
            ushort4 h; h.x = f2bf(w.x); h.y = f2bf(w.y); h.z = f2bf(w.z); h.w = f2bf(w.w);
            *reinterpret_cast<ushort4*>(hrow + (col & ~31) * 2 + ((((col >> 3) & 3) ^ fr) << 4) + (col & 7) * 2) = h;
        }
        for (int off = 32; off; off >>= 1) acc += __shfl_xor(acc, off);
        if (lane == 0) ws_f[r] = acc;          // vab
    }
    {
        const float* wrow = Wag + (size_t)r * DIN;
        char* hrow = (char*)Whag + (size_t)r * DIN * 2;
        float acc = 0.f;
#pragma unroll
        for (int it = 0; it < 4; ++it) {
            int col = it * 256 + lane * 4;
            float4 w = *reinterpret_cast<const float4*>(wrow + col);
            float4 bv = *reinterpret_cast<const float4*>(bab + col);
            acc += w.x * bv.x + w.y * bv.y + w.z * bv.z + w.w * bv.w;
            ushort4 h; h.x = f2bf(w.x); h.y = f2bf(w.y); h.z = f2bf(w.z); h.w = f2bf(w.w);
            *reinterpret_cast<ushort4*>(hrow + (col & ~31) * 2 + ((((col >> 3) & 3) ^ fr) << 4) + (col & 7) * 2) = h;
        }
        for (int off = 32; off; off >>= 1) acc += __shfl_xor(acc, off);
        if (lane == 0) ws_f[1024 + r] = acc;   // vag
    }
}

// ---- Kernel B (combo): blocks [0,256) = mt role; blocks [256,2304) = stream role ----
__global__ __launch_bounds__(256) void combo_kernel(const unsigned short* __restrict__ Whag,
                                                    const unsigned short* __restrict__ Whab,
                                                    unsigned short* __restrict__ Mt,
                                                    const float* __restrict__ gAB,
                                                    const float* __restrict__ sAB,
                                                    const float* __restrict__ sAG,
                                                    const float* __restrict__ ws_f,
                                                    unsigned short* __restrict__ gABh,
                                                    float* __restrict__ out,
                                                    int writecast) {
    __shared__ unsigned short sm[2][2][2][2048];   // 32 KB (mt role)
    int b = blockIdx.x;
    int tid = threadIdx.x, wave = tid >> 6, lane = tid & 63;

    if (b < 256) {
        // mt role: Mt[l,k] = Wag[l,:].Wab[k,:], 64x64 tile, 2 K-groups x 2 waves
        int grp = wave >> 1, w2 = wave & 1;
        int kg = lane >> 4, cl = lane & 15;
        int br = b >> 4, bc = b & 15;
        int u = tid & 127;

        const char* Abase = (const char*)Whag + ((size_t)(br * 64) * DIN + grp * 512) * 2;
        const char* Bbase = (const char*)Whab + ((size_t)(bc * 64) * DIN + grp * 512) * 2;

        int offA[2], offB[4];
#pragma unroll
        for (int m = 0; m < 2; ++m) { int row = w2 * 32 + m * 16 + cl; offA[m] = row * 32 + ((kg ^ fswz(row)) << 3); }
#pragma unroll
        for (int n = 0; n < 4; ++n) { int row = n * 16 + cl; offB[n] = row * 32 + ((kg ^ fswz(row)) << 3); }

        f32x4 acc[2][4] = {};
#define STAGE_MT(buf, t)                                                            \
        _Pragma("unroll")                                                           \
        for (int it = 0; it < 2; ++it) {                                            \
            int un = u + it * 128, urow = un >> 2, uc = un & 3;                     \
            gload_lds16(Abase + (size_t)urow * 2048 + (t) * 64 + uc * 16,           \
                        &sm[grp][buf][0][un * 8]);                                  \
            gload_lds16(Bbase + (size_t)urow * 2048 + (t) * 64 + uc * 16,           \
                        &sm[grp][buf][1][un * 8]);                                  \
        }
        STAGE_MT(0, 0);
        for (int t = 0; t < 16; ++t) {
            int p = t & 1;
            __syncthreads();
            if (t < 15) { STAGE_MT(p ^ 1, t + 1); }
            bf16x8 af[2], bfr[4];
#pragma unroll
            for (int m = 0; m < 2; ++m) af[m] = *reinterpret_cast<const bf16x8*>(&sm[grp][p][0][offA[m]]);
#pragma unroll
            for (int n = 0; n < 4; ++n) bfr[n] = *reinterpret_cast<const bf16x8*>(&sm[grp][p][1][offB[n]]);
            __builtin_amdgcn_s_setprio(1);
#pragma unroll
            for (int m = 0; m < 2; ++m)
#pragma unroll
                for (int n = 0; n < 4; ++n)
                    acc[m][n] = __builtin_amdgcn_mfma_f32_16x16x32_bf16(af[m], bfr[n], acc[m][n], 0, 0, 0);
            __builtin_amdgcn_s_setprio(0);
        }
#undef STAGE_MT
        __syncthreads();
        float* red = (float*)sm;   // [64][68] padded
        if (grp == 1) {
#pragma unroll
            for (int m = 0; m < 2; ++m)
#pragma unroll
                for (int n = 0; n < 4; ++n)
#pragma unroll
                    for (int j = 0; j < 4; ++j)
                        red[(w2 * 32 + m * 16 + kg * 4 + j) * 68 + n * 16 + cl] = acc[m][n][j];
        }
        __syncthreads();
        if (grp == 0) {
#pragma unroll
            for (int m = 0; m < 2; ++m)
#pragma unroll
                for (int n = 0; n < 4; ++n)
#pragma unroll
                    for (int j = 0; j < 4; ++j) {
                        int rl = w2 * 32 + m * 16 + kg * 4 + j, cll = n * 16 + cl;
                        float v = acc[m][n][j] + red[rl * 68 + cll];
                        int R = br * 64 + rl, C = bc * 64 + cll;
                        *(unsigned short*)((char*)Mt + swz_byte(R, C)) = f2bf(v);
                    }
        }
        return;
    }

    // stream role: h2 + Term2 + c; cast gAB -> gABh (fswz4)
    int row = (b - 256) * 4 + wave;
    const float* ga = gAB + (size_t)row * DIN;
    const float* sa = sAB + (size_t)row * DIN;
    const float* sg = sAG + (size_t)row * DIN;
    char* gh = (char*)gABh + (size_t)row * DIN * 2;
    int fr = fswz(row);
    float acc = 0.f;
#pragma unroll
    for (int cc = 0; cc < 4; ++cc) {
        int col = cc * 256 + lane * 4;
        float4 a = *reinterpret_cast<const float4*>(ga + col);
        float4 x = *reinterpret_cast<const float4*>(sa + col);
        float4 y = *reinterpret_cast<const float4*>(sg + col);
        float4 v = *reinterpret_cast<const float4*>(ws_f + col);   // vab
        acc += x.x * y.x + x.y * y.y + x.z * y.z + x.w * y.w;
        acc += a.x * v.x + a.y * v.y + a.z * v.z + a.w * v.w;
        if (writecast) {
            ushort4 h; h.x = f2bf(a.x); h.y = f2bf(a.y); h.z = f2bf(a.z); h.w = f2bf(a.w);
            *reinterpret_cast<ushort4*>(gh + (col & ~31) * 2 + ((((col >> 3) & 3) ^ fr) << 4) + (col & 7) * 2) = h;
        }
    }
#pragma unroll
    for (int off = 32; off; off >>= 1) acc += __shfl_xor(acc, off);
    if (lane == 0) out[row] = 0.5f * (acc + ws_f[2048]);
}

// ---- Kernel C: 256^2 tile, BK=32, KSPLIT=4 -> 512 blocks = 2 blocks/CU.
//      Halves staged bytes/FLOP vs 128^2 while keeping cross-block latency
//      overlap. 8 waves (2M x 4N), wave tile 128x64, stage-after-barrier. ----
__global__ __launch_bounds__(512, 4) void gemm256k4(const unsigned short* __restrict__ gABh,
                                                    const float* __restrict__ gAG,
                                                    const unsigned short* __restrict__ Mt,
                                                    const float* __restrict__ ws_f,
                                                    float* __restrict__ out) {
    __shared__ unsigned short lds_a[2][256 * 32];   // 16 KB per buf -> 32 KB
    __shared__ unsigned short lds_b[2][256 * 32];   // 32 KB (total 64 KB -> 2 blocks/CU)
    constexpr int NSTEP = 8;                        // KLEN = 256, BK = 32
    int b = blockIdx.x;
    int x = b & 7, s = b >> 3;        // XCD map: same-rblk blocks share an XCD
    int rblk = x + 8 * (s & 3);       // 0..31
    int rem = s >> 2;                 // 0..15
    int ks = rem & 3;                 // 0..3
    int cblk = rem >> 2;              // 0..3
    int tid = threadIdx.x, wave = tid >> 6, lane = tid & 63;
    int wr = wave >> 2, wc = wave & 3;        // 2(M) x 4(N)
    int kg = lane >> 4, cl = lane & 15;
    int row0 = rblk * 256, col0 = cblk * 256;

    const char* Ab = (const char*)gABh + (size_t)row0 * 2048 + ks * 512;
    const char* Bb = (const char*)Mt + (size_t)col0 * 2048 + ks * 512;

    // ds_read byte offsets (fswz4, R14-verified)
    int offA[8], offB[4];
#pragma unroll
    for (int m = 0; m < 8; ++m) { int row = wr * 128 + m * 16 + cl; offA[m] = row * 64 + ((kg ^ fswz(row)) << 4); }
#pragma unroll
    for (int n = 0; n < 4; ++n) { int row = wc * 64 + n * 16 + cl; offB[n] = row * 64 + ((kg ^ fswz(row)) << 4); }

    // staging: per tile 1024 16B-units per operand; 512 threads -> 2 units each.
    // unit u: row = u>>2, chunk = u&3; one 64B group per row per BK=32 slice, so
    // a linear 64B copy preserves the fswz4 storage swizzle.
#define STAGE(buf, t) do {                                                          \
    _Pragma("unroll")                                                               \
    for (int it = 0; it < 2; ++it) {                                                \
        int u = tid + it * 512;                                                     \
        int row_ = u >> 2, c_ = u & 3;                                              \
        gload_lds16(Ab + (size_t)row_ * 2048 + (t) * 64 + c_ * 16,                  \
                    (char*)&lds_a[buf][0] + u * 16);                                \
    }                                                                               \
    _Pragma("unroll")                                                               \
    for (int it = 0; it < 2; ++it) {                                                \
        int u = tid + it * 512;                                                     \
        int row_ = u >> 2, c_ = u & 3;                                              \
        gload_lds16(Bb + (size_t)row_ * 2048 + (t) * 64 + c_ * 16,                  \
                    (char*)&lds_b[buf][0] + u * 16);                                \
    }                                                                               \
} while (0)

    f32x4 acc[8][4] = {};

    STAGE(0, 0);
    for (int t = 0; t < NSTEP; ++t) {
        int p = t & 1;
        __syncthreads();    // drains tile-t loads (t+1 not yet staged)
        if (t < NSTEP - 1) { STAGE(p ^ 1, t + 1); }
        bf16x8 bfr[4];
#pragma unroll
        for (int n = 0; n < 4; ++n) bfr[n] = *reinterpret_cast<const bf16x8*>((char*)&lds_b[p][0] + offB[n]);
#pragma unroll
        for (int m = 0; m < 8; ++m) {
            bf16x8 af = *reinterpret_cast<const bf16x8*>((char*)&lds_a[p][0] + offA[m]);
            __builtin_amdgcn_s_setprio(1);
#pragma unroll
            for (int n = 0; n < 4; ++n)
                acc[m][n] = __builtin_amdgcn_mfma_f32_16x16x32_bf16(af, bfr[n], acc[m][n], 0, 0, 0);
            __builtin_amdgcn_s_setprio(0);
        }
    }
#undef STAGE

    // epilogue: Term1 (all ks) + Term3 (ks==0 only); gAG kept fp32
    const float* vag = ws_f + 1024;
#pragma unroll
    for (int m = 0; m < 8; ++m)
#pragma unroll
        for (int j = 0; j < 4; ++j) {
            int row = row0 + wr * 128 + m * 16 + kg * 4 + j;
            const float* gr = gAG + (size_t)row * DIN;
            float tt = 0.f;
#pragma unroll
            for (int n = 0; n < 4; ++n) {
                int col = col0 + wc * 64 + n * 16 + cl;
                float addv = (ks == 0) ? vag[col] : 0.f;
                tt += gr[col] * (acc[m][n][j] + addv);
            }
            tt += __shfl_xor(tt, 1);
            tt += __shfl_xor(tt, 2);
            tt += __shfl_xor(tt, 4);
            tt += __shfl_xor(tt, 8);
            if (cl == 0) atomicAdd(out + row, 0.5f * tt);
        }
}

// ---- fallback GEMM (small ws): fp32 reg-stage 128^2, KSPLIT=2 (R8 path) ----
__global__ __launch_bounds__(256, 4) void gemm_fb(const float* __restrict__ gAB,
                                                  const float* __restrict__ gAG,
                                                  const unsigned short* __restrict__ Mt,
                                                  const float* __restrict__ ws_f,
                                                  float* __restrict__ out) {
    __shared__ unsigned short lds_a[2][128 * 32];
    __shared__ unsigned short lds_b[2][128 * 32];
    constexpr int KSPLIT = 2, KLEN = DIN / KSPLIT, NSTEP = KLEN / 32;
    int b = blockIdx.x;
    int x = b & 7, s = b >> 3;
    int rblk = x + 8 * (s & 7);
    int u2 = s >> 3;
    int ks = u2 & (KSPLIT - 1);
    int cblk = u2 / KSPLIT;
    int tid = threadIdx.x, wave = tid >> 6, lane = tid & 63;
    int wr = wave >> 1, wc = wave & 1;
    int kg = lane >> 4, cl = lane & 15;
    int row0 = rblk * 128, col0 = cblk * 128;

    int offA[4], offB[4];
#pragma unroll
    for (int m = 0; m < 4; ++m) { int row = wr * 64 + m * 16 + cl; offA[m] = row * 64 + ((kg ^ fswz(row)) << 4); }
#pragma unroll
    for (int n = 0; n < 4; ++n) { int row = wc * 64 + n * 16 + cl; offB[n] = row * 64 + ((kg ^ fswz(row)) << 4); }

    const float* Af = gAB + (size_t)row0 * DIN + ks * KLEN;
    const char* Bb = (const char*)Mt + ((size_t)col0 * DIN + ks * KLEN) * 2;

    f32x4 acc[4][4] = {};
    float4 ra[4];
#define STAGE_A(buf, t)                                                             \
    _Pragma("unroll")                                                               \
    for (int it = 0; it < 4; ++it) {                                                \
        int u = tid + it * 256, row_ = u >> 3, c4 = u & 7;                          \
        ra[it] = *reinterpret_cast<const float4*>(Af + (size_t)row_ * DIN + (t) * 32 + c4 * 4); \
    }                                                                               \
    _Pragma("unroll")                                                               \
    for (int it = 0; it < 4; ++it) {                                                \
        int u = tid + it * 256, row_ = u >> 3, c4 = u & 7;                          \
        ushort4 h; h.x = f2bf(ra[it].x); h.y = f2bf(ra[it].y); h.z = f2bf(ra[it].z); h.w = f2bf(ra[it].w); \
        *reinterpret_cast<ushort4*>((char*)&lds_a[buf][0] + row_ * 64 +             \
                                    (((c4 >> 1) ^ fswz(row_)) << 4) + (c4 & 1) * 8) = h; \
    }
#define STAGE_Bm(buf, t)                                                            \
    _Pragma("unroll")                                                               \
    for (int it = 0; it < 2; ++it) {                                                \
        int u = tid + it * 256, row_ = u >> 2, c_ = u & 3;                          \
        gload_lds16(Bb + (size_t)row_ * 2048 + (t) * 64 + c_ * 16,                  \
                    (char*)&lds_b[buf][0] + u * 16);                                \
    }
    STAGE_A(0, 0);
    STAGE_Bm(0, 0);
    for (int t = 0; t < NSTEP; ++t) {
        int p = t & 1;
        __syncthreads();
        if (t < NSTEP - 1) { STAGE_Bm(p ^ 1, t + 1); }
        bf16x8 af[4], bfr[4];
#pragma unroll
        for (int m = 0; m < 4; ++m) af[m] = *reinterpret_cast<const bf16x8*>((char*)&lds_a[p][0] + offA[m]);
#pragma unroll
        for (int n = 0; n < 4; ++n) bfr[n] = *reinterpret_cast<const bf16x8*>((char*)&lds_b[p][0] + offB[n]);
#pragma unroll
        for (int m = 0; m < 4; ++m)
#pragma unroll
            for (int n = 0; n < 4; ++n)
                acc[m][n] = __builtin_amdgcn_mfma_f32_16x16x32_bf16(af[m], bfr[n], acc[m][n], 0, 0, 0);
        if (t < NSTEP - 1) { STAGE_A(p ^ 1, t + 1); }
    }
#undef STAGE_A
#undef STAGE_Bm
    const float* vag = ws_f + 1024;
#pragma unroll
    for (int m = 0; m < 4; ++m)
#pragma unroll
        for (int j = 0; j < 4; ++j) {
            int row = row0 + wr * 64 + m * 16 + kg * 4 + j;
            const float* gr = gAG + (size_t)row * DIN;
            float tt = 0.f;
#pragma unroll
            for (int n = 0; n < 4; ++n) {
                int col = col0 + wc * 64 + n * 16 + cl;
                float addv = (ks == 0) ? vag[col] : 0.f;
                tt += gr[col] * (acc[m][n][j] + addv);
            }
            tt += __shfl_xor(tt, 1);
            tt += __shfl_xor(tt, 2);
            tt += __shfl_xor(tt, 4);
            tt += __shfl_xor(tt, 8);
            if (cl == 0) atomicAdd(out + row, 0.5f * tt);
        }
}

extern "C" void kernel_launch(void* const* d_in, const int* in_sizes, int n_in,
                              void* d_out, int out_size, void* d_ws, size_t ws_size,
                              hipStream_t stream) {
    const float* gAB = (const float*)d_in[0];
    const float* gAG = (const float*)d_in[1];
    const float* Wab = (const float*)d_in[2];
    const float* Wag = (const float*)d_in[3];
    const float* bab = (const float*)d_in[4];
    const float* bag = (const float*)d_in[5];
    const float* sAB = (const float*)d_in[6];
    const float* sAG = (const float*)d_in[7];
    float* out = (float*)d_out;

    // ws layout: ws_f 16KB | Mt 2MB | Whag 2MB | Whab 2MB | gABh 16MB
    float* ws_f = (float*)d_ws;
    char* base = (char*)d_ws + 16384;
    unsigned short* Mt = (unsigned short*)base;
    unsigned short* Whag = (unsigned short*)(base + (size_t)2 * 1024 * 1024);
    unsigned short* Whab = (unsigned short*)(base + (size_t)4 * 1024 * 1024);
    unsigned short* gABh = (unsigned short*)(base + (size_t)6 * 1024 * 1024);
    size_t need_full = 16384 + (size_t)22 * 1024 * 1024;
    int precast = (ws_size >= need_full) ? 1 : 0;

    prep_kernel<<<257, 256, 0, stream>>>(Wab, Wag, bab, bag, ws_f, Whab, Whag);
    combo_kernel<<<2304, 256, 0, stream>>>(Whag, Whab, Mt, gAB, sAB, sAG, ws_f, gABh, out, precast);
    if (precast)
        gemm256k4<<<512, 512, 0, stream>>>(gABh, gAG, Mt, ws_f, out);
    else
        gemm_fb<<<1024, 256, 0, stream>>>(gAB, gAG, Mt, ws_f, out);
}

// Round 16
// 61.505 us; speedup vs baseline: 2.4543x; 2.4543x over previous
//
#include <hip/hip_runtime.h>
#include <hip/hip_bf16.h>
#include <stdint.h>

typedef __attribute__((ext_vector_type(8))) short bf16x8;
typedef __attribute__((ext_vector_type(4))) float f32x4;

#define DIN 1024
#define NROWS 8192

__device__ __forceinline__ unsigned short f2bf(float f) {
    union { float f; unsigned u; } v; v.f = f;
    unsigned r = v.u + 0x7FFFu + ((v.u >> 16) & 1u);  // RNE
    return (unsigned short)(r >> 16);
}

__device__ __forceinline__ int fswz(int r) { return (r ^ (r >> 2)) & 3; }

// byte offset of bf16 element (R,c) in row-major [*,1024] stored with 16B-chunk
// XOR swizzle (chunk ^= fswz(R)) within 64B groups
__device__ __forceinline__ size_t swz_byte(int R, int c) {
    return ((size_t)R * DIN + (size_t)(c & ~31)) * 2
         + (size_t)((((c >> 3) & 3) ^ fswz(R)) << 4)
         + (size_t)((c & 7) * 2);
}

__device__ __forceinline__ void gload_lds16(const void* g, void* l) {
    __builtin_amdgcn_global_load_lds(
        (const __attribute__((address_space(1))) unsigned*)g,
        (__attribute__((address_space(3))) unsigned*)l, 16, 0, 0);
}

// ---- Kernel A: vab/vag/c + cast Wab,Wag -> bf16 (fswz4) ----
__global__ __launch_bounds__(256) void prep_kernel(const float* __restrict__ Wab,
                                                   const float* __restrict__ Wag,
                                                   const float* __restrict__ bab,
                                                   const float* __restrict__ bag,
                                                   float* __restrict__ ws_f,
                                                   unsigned short* __restrict__ Whab,
                                                   unsigned short* __restrict__ Whag) {
    int b = blockIdx.x;
    int wave = threadIdx.x >> 6, lane = threadIdx.x & 63;
    if (b == 256) {
        if (wave == 0) {
            float acc = 0.f;
            for (int j = lane; j < DIN; j += 64) acc += bab[j] * bag[j];
            for (int off = 32; off; off >>= 1) acc += __shfl_xor(acc, off);
            if (lane == 0) ws_f[2048] = acc;
        }
        return;
    }
    int r = b * 4 + wave;
    int fr = fswz(r);
    {
        const float* wrow = Wab + (size_t)r * DIN;
        char* hrow = (char*)Whab + (size_t)r * DIN * 2;
        float acc = 0.f;
#pragma unroll
        for (int it = 0; it < 4; ++it) {
            int col = it * 256 + lane * 4;
            float4 w = *reinterpret_cast<const float4*>(wrow + col);
            float4 bv = *reinterpret_cast<const float4*>(bag + col);
            acc += w.x * bv.x + w.y * bv.y + w.z * bv.z + w.w * bv.w;
            ushort4 h; h.x = f2bf(w.x); h.y = f2bf(w.y); h.z = f2bf(w.z); h.w = f2bf(w.w);
            *reinterpret_cast<ushort4*>(hrow + (col & ~31) * 2 + ((((col >> 3) & 3) ^ fr) << 4) + (col & 7) * 2) = h;
        }
        for (int off = 32; off; off >>= 1) acc += __shfl_xor(acc, off);
        if (lane == 0) ws_f[r] = acc;          // vab
    }
    {
        const float* wrow = Wag + (size_t)r * DIN;
        char* hrow = (char*)Whag + (size_t)r * DIN * 2;
        float acc = 0.f;
#pragma unroll
        for (int it = 0; it < 4; ++it) {
            int col = it * 256 + lane * 4;
            float4 w = *reinterpret_cast<const float4*>(wrow + col);
            float4 bv = *reinterpret_cast<const float4*>(bab + col);
            acc += w.x * bv.x + w.y * bv.y + w.z * bv.z + w.w * bv.w;
            ushort4 h; h.x = f2bf(w.x); h.y = f2bf(w.y); h.z = f2bf(w.z); h.w = f2bf(w.w);
            *reinterpret_cast<ushort4*>(hrow + (col & ~31) * 2 + ((((col >> 3) & 3) ^ fr) << 4) + (col & 7) * 2) = h;
        }
        for (int off = 32; off; off >>= 1) acc += __shfl_xor(acc, off);
        if (lane == 0) ws_f[1024 + r] = acc;   // vag
    }
}

// ---- Kernel B (combo): blocks [0,256) = mt role (dispatched FIRST, hides under
//      stream); blocks [256,2304) = stream role. ----
__global__ __launch_bounds__(256) void combo_kernel(const unsigned short* __restrict__ Whag,
                                                    const unsigned short* __restrict__ Whab,
                                                    unsigned short* __restrict__ Mt,
                                                    const float* __restrict__ gAB,
                                                    const float* __restrict__ sAB,
                                                    const float* __restrict__ sAG,
                                                    const float* __restrict__ ws_f,
                                                    unsigned short* __restrict__ gABh,
                                                    float* __restrict__ out,
                                                    int writecast) {
    __shared__ unsigned short sm[2][2][2][2048];   // 32 KB (mt role)
    int b = blockIdx.x;
    int tid = threadIdx.x, wave = tid >> 6, lane = tid & 63;

    if (b < 256) {
        // mt role: Mt[l,k] = Wag[l,:].Wab[k,:], 64x64 tile, 2 K-groups x 2 waves
        int grp = wave >> 1, w2 = wave & 1;
        int kg = lane >> 4, cl = lane & 15;
        int br = b >> 4, bc = b & 15;
        int u = tid & 127;

        const char* Abase = (const char*)Whag + ((size_t)(br * 64) * DIN + grp * 512) * 2;
        const char* Bbase = (const char*)Whab + ((size_t)(bc * 64) * DIN + grp * 512) * 2;

        int offA[2], offB[4];
#pragma unroll
        for (int m = 0; m < 2; ++m) { int row = w2 * 32 + m * 16 + cl; offA[m] = row * 32 + ((kg ^ fswz(row)) << 3); }
#pragma unroll
        for (int n = 0; n < 4; ++n) { int row = n * 16 + cl; offB[n] = row * 32 + ((kg ^ fswz(row)) << 3); }

        f32x4 acc[2][4] = {};
#define STAGE_MT(buf, t)                                                            \
        _Pragma("unroll")                                                           \
        for (int it = 0; it < 2; ++it) {                                            \
            int un = u + it * 128, urow = un >> 2, uc = un & 3;                     \
            gload_lds16(Abase + (size_t)urow * 2048 + (t) * 64 + uc * 16,           \
                        &sm[grp][buf][0][un * 8]);                                  \
            gload_lds16(Bbase + (size_t)urow * 2048 + (t) * 64 + uc * 16,           \
                        &sm[grp][buf][1][un * 8]);                                  \
        }
        STAGE_MT(0, 0);
        for (int t = 0; t < 16; ++t) {
            int p = t & 1;
            __syncthreads();
            if (t < 15) { STAGE_MT(p ^ 1, t + 1); }
            bf16x8 af[2], bfr[4];
#pragma unroll
            for (int m = 0; m < 2; ++m) af[m] = *reinterpret_cast<const bf16x8*>(&sm[grp][p][0][offA[m]]);
#pragma unroll
            for (int n = 0; n < 4; ++n) bfr[n] = *reinterpret_cast<const bf16x8*>(&sm[grp][p][1][offB[n]]);
            __builtin_amdgcn_s_setprio(1);
#pragma unroll
            for (int m = 0; m < 2; ++m)
#pragma unroll
                for (int n = 0; n < 4; ++n)
                    acc[m][n] = __builtin_amdgcn_mfma_f32_16x16x32_bf16(af[m], bfr[n], acc[m][n], 0, 0, 0);
            __builtin_amdgcn_s_setprio(0);
        }
#undef STAGE_MT
        __syncthreads();
        float* red = (float*)sm;   // [64][68] padded
        if (grp == 1) {
#pragma unroll
            for (int m = 0; m < 2; ++m)
#pragma unroll
                for (int n = 0; n < 4; ++n)
#pragma unroll
                    for (int j = 0; j < 4; ++j)
                        red[(w2 * 32 + m * 16 + kg * 4 + j) * 68 + n * 16 + cl] = acc[m][n][j];
        }
        __syncthreads();
        if (grp == 0) {
#pragma unroll
            for (int m = 0; m < 2; ++m)
#pragma unroll
                for (int n = 0; n < 4; ++n)
#pragma unroll
                    for (int j = 0; j < 4; ++j) {
                        int rl = w2 * 32 + m * 16 + kg * 4 + j, cll = n * 16 + cl;
                        float v = acc[m][n][j] + red[rl * 68 + cll];
                        int R = br * 64 + rl, C = bc * 64 + cll;
                        *(unsigned short*)((char*)Mt + swz_byte(R, C)) = f2bf(v);
                    }
        }
        return;
    }

    // stream role: h2 + Term2 + c; cast gAB -> gABh (fswz4)
    int row = (b - 256) * 4 + wave;
    const float* ga = gAB + (size_t)row * DIN;
    const float* sa = sAB + (size_t)row * DIN;
    const float* sg = sAG + (size_t)row * DIN;
    char* gh = (char*)gABh + (size_t)row * DIN * 2;
    int fr = fswz(row);
    float acc = 0.f;
#pragma unroll
    for (int cc = 0; cc < 4; ++cc) {
        int col = cc * 256 + lane * 4;
        float4 a = *reinterpret_cast<const float4*>(ga + col);
        float4 x = *reinterpret_cast<const float4*>(sa + col);
        float4 y = *reinterpret_cast<const float4*>(sg + col);
        float4 v = *reinterpret_cast<const float4*>(ws_f + col);   // vab
        acc += x.x * y.x + x.y * y.y + x.z * y.z + x.w * y.w;
        acc += a.x * v.x + a.y * v.y + a.z * v.z + a.w * v.w;
        if (writecast) {
            ushort4 h; h.x = f2bf(a.x); h.y = f2bf(a.y); h.z = f2bf(a.z); h.w = f2bf(a.w);
            *reinterpret_cast<ushort4*>(gh + (col & ~31) * 2 + ((((col >> 3) & 3) ^ fr) << 4) + (col & 7) * 2) = h;
        }
    }
#pragma unroll
    for (int off = 32; off; off >>= 1) acc += __shfl_xor(acc, off);
    if (lane == 0) out[row] = 0.5f * (acc + ws_f[2048]);
}

// ---- Kernel C: P = gAB @ Mt^T fused Term1+Term3 (stage-after-barrier) ----
template <int PRECAST, int KSPLIT>
__global__ __launch_bounds__(256, 4) void gemm_kernel(const float* __restrict__ gAB,
                                                      const unsigned short* __restrict__ gABh,
                                                      const float* __restrict__ gAG,
                                                      const unsigned short* __restrict__ Mt,
                                                      const float* __restrict__ ws_f,
                                                      float* __restrict__ out) {
    __shared__ unsigned short lds_a[2][128 * 32];
    __shared__ unsigned short lds_b[2][128 * 32];
    constexpr int KLEN = DIN / KSPLIT;
    constexpr int NSTEP = KLEN / 32;
    int b = blockIdx.x;
    int x = b & 7, s = b >> 3;
    int rblk = x + 8 * (s & 7);
    int u2 = s >> 3;
    int ks = u2 & (KSPLIT - 1);
    int cblk = u2 / KSPLIT;
    int tid = threadIdx.x, wave = tid >> 6, lane = tid & 63;
    int wr = wave >> 1, wc = wave & 1;
    int kg = lane >> 4, cl = lane & 15;
    int row0 = rblk * 128, col0 = cblk * 128;

    int offA[4], offB[4];
#pragma unroll
    for (int m = 0; m < 4; ++m) { int row = wr * 64 + m * 16 + cl; offA[m] = row * 32 + ((kg ^ fswz(row)) << 3); }
#pragma unroll
    for (int n = 0; n < 4; ++n) { int row = wc * 64 + n * 16 + cl; offB[n] = row * 32 + ((kg ^ fswz(row)) << 3); }

    size_t kofs = (size_t)(ks * KLEN) * 2;
    const char* Ab = (const char*)gABh + (size_t)row0 * DIN * 2 + kofs;
    const char* Bb = (const char*)Mt + (size_t)col0 * DIN * 2 + kofs;
    int u0 = tid, u1 = tid + 256;
    size_t a0 = (size_t)(u0 >> 2) * (DIN * 2) + (u0 & 3) * 16;
    size_t a1 = (size_t)(u1 >> 2) * (DIN * 2) + (u1 & 3) * 16;

    f32x4 acc[4][4] = {};
    float4 ra[4];
    if (PRECAST) {
        gload_lds16(Ab + a0, (char*)&lds_a[0][0] + u0 * 16);
        gload_lds16(Ab + a1, (char*)&lds_a[0][0] + u1 * 16);
        gload_lds16(Bb + a0, (char*)&lds_b[0][0] + u0 * 16);
        gload_lds16(Bb + a1, (char*)&lds_b[0][0] + u1 * 16);

        for (int t = 0; t < NSTEP; ++t) {
            int p = t & 1;
            __syncthreads();
            if (t < NSTEP - 1) {
                gload_lds16(Ab + a0 + (t + 1) * 64, (char*)&lds_a[p ^ 1][0] + u0 * 16);
                gload_lds16(Ab + a1 + (t + 1) * 64, (char*)&lds_a[p ^ 1][0] + u1 * 16);
                gload_lds16(Bb + a0 + (t + 1) * 64, (char*)&lds_b[p ^ 1][0] + u0 * 16);
                gload_lds16(Bb + a1 + (t + 1) * 64, (char*)&lds_b[p ^ 1][0] + u1 * 16);
            }
            bf16x8 af[4], bfr[4];
#pragma unroll
            for (int m = 0; m < 4; ++m) af[m] = *reinterpret_cast<const bf16x8*>(&lds_a[p][offA[m]]);
#pragma unroll
            for (int n = 0; n < 4; ++n) bfr[n] = *reinterpret_cast<const bf16x8*>(&lds_b[p][offB[n]]);
            __builtin_amdgcn_s_setprio(1);
#pragma unroll
            for (int m = 0; m < 4; ++m)
#pragma unroll
                for (int n = 0; n < 4; ++n)
                    acc[m][n] = __builtin_amdgcn_mfma_f32_16x16x32_bf16(af[m], bfr[n], acc[m][n], 0, 0, 0);
            __builtin_amdgcn_s_setprio(0);
        }
    } else {
#pragma unroll
        for (int it = 0; it < 4; ++it) {
            int u = tid + it * 256;
            ra[it] = *reinterpret_cast<const float4*>(gAB + (size_t)(row0 + (u >> 3)) * DIN + ks * KLEN + (u & 7) * 4);
        }
#pragma unroll
        for (int it = 0; it < 4; ++it) {
            int u = tid + it * 256, row = u >> 3, c4 = u & 7;
            ushort4 h; h.x = f2bf(ra[it].x); h.y = f2bf(ra[it].y); h.z = f2bf(ra[it].z); h.w = f2bf(ra[it].w);
            *reinterpret_cast<ushort4*>((char*)&lds_a[0][0] + row * 64 + ((((c4 >> 1) ^ fswz(row))) << 4) + (c4 & 1) * 8) = h;
        }
        gload_lds16(Bb + a0, (char*)&lds_b[0][0] + u0 * 16);
        gload_lds16(Bb + a1, (char*)&lds_b[0][0] + u1 * 16);
        for (int t = 0; t < NSTEP; ++t) {
            int p = t & 1;
            __syncthreads();
            if (t < NSTEP - 1) {
#pragma unroll
                for (int it = 0; it < 4; ++it) {
                    int u = tid + it * 256;
                    ra[it] = *reinterpret_cast<const float4*>(gAB + (size_t)(row0 + (u >> 3)) * DIN + ks * KLEN + (t + 1) * 32 + (u & 7) * 4);
                }
                gload_lds16(Bb + a0 + (t + 1) * 64, (char*)&lds_b[p ^ 1][0] + u0 * 16);
                gload_lds16(Bb + a1 + (t + 1) * 64, (char*)&lds_b[p ^ 1][0] + u1 * 16);
            }
            bf16x8 af[4], bfr[4];
#pragma unroll
            for (int m = 0; m < 4; ++m) af[m] = *reinterpret_cast<const bf16x8*>(&lds_a[p][offA[m]]);
#pragma unroll
            for (int n = 0; n < 4; ++n) bfr[n] = *reinterpret_cast<const bf16x8*>(&lds_b[p][offB[n]]);
#pragma unroll
            for (int m = 0; m < 4; ++m)
#pragma unroll
                for (int n = 0; n < 4; ++n)
                    acc[m][n] = __builtin_amdgcn_mfma_f32_16x16x32_bf16(af[m], bfr[n], acc[m][n], 0, 0, 0);
            if (t < NSTEP - 1) {
#pragma unroll
                for (int it = 0; it < 4; ++it) {
                    int u = tid + it * 256, row = u >> 3, c4 = u & 7;
                    ushort4 h; h.x = f2bf(ra[it].x); h.y = f2bf(ra[it].y); h.z = f2bf(ra[it].z); h.w = f2bf(ra[it].w);
                    *reinterpret_cast<ushort4*>((char*)&lds_a[p ^ 1][0] + row * 64 + ((((c4 >> 1) ^ fswz(row))) << 4) + (c4 & 1) * 8) = h;
                }
            }
        }
    }

    const float* vag = ws_f + 1024;
#pragma unroll
    for (int m = 0; m < 4; ++m)
#pragma unroll
        for (int j = 0; j < 4; ++j) {
            int row = row0 + wr * 64 + m * 16 + kg * 4 + j;
            const float* gr = gAG + (size_t)row * DIN;
            float t = 0.f;
#pragma unroll
            for (int n = 0; n < 4; ++n) {
                int col = col0 + wc * 64 + n * 16 + cl;
                float addv = (ks == 0) ? vag[col] : 0.f;
                t += gr[col] * (acc[m][n][j] + addv);
            }
            t += __shfl_xor(t, 1);
            t += __shfl_xor(t, 2);
            t += __shfl_xor(t, 4);
            t += __shfl_xor(t, 8);
            if (cl == 0) atomicAdd(out + row, 0.5f * t);
        }
}

extern "C" void kernel_launch(void* const* d_in, const int* in_sizes, int n_in,
                              void* d_out, int out_size, void* d_ws, size_t ws_size,
                              hipStream_t stream) {
    const float* gAB = (const float*)d_in[0];
    const float* gAG = (const float*)d_in[1];
    const float* Wab = (const float*)d_in[2];
    const float* Wag = (const float*)d_in[3];
    const float* bab = (const float*)d_in[4];
    const float* bag = (const float*)d_in[5];
    const float* sAB = (const float*)d_in[6];
    const float* sAG = (const float*)d_in[7];
    float* out = (float*)d_out;

    // ws layout: ws_f 16KB | Mt 2MB | Whag 2MB | Whab 2MB | gABh 16MB
    float* ws_f = (float*)d_ws;
    char* base = (char*)d_ws + 16384;
    unsigned short* Mt = (unsigned short*)base;
    unsigned short* Whag = (unsigned short*)(base + (size_t)2 * 1024 * 1024);
    unsigned short* Whab = (unsigned short*)(base + (size_t)4 * 1024 * 1024);
    unsigned short* gABh = (unsigned short*)(base + (size_t)6 * 1024 * 1024);
    size_t need_full = 16384 + (size_t)22 * 1024 * 1024;
    int precast = (ws_size >= need_full) ? 1 : 0;

    prep_kernel<<<257, 256, 0, stream>>>(Wab, Wag, bab, bag, ws_f, Whab, Whag);
    combo_kernel<<<2304, 256, 0, stream>>>(Whag, Whab, Mt, gAB, sAB, sAG, ws_f, gABh, out, precast);
    if (precast)
        gemm_kernel<1, 2><<<1024, 256, 0, stream>>>(gAB, gABh, gAG, Mt, ws_f, out);
    else
        gemm_kernel<0, 2><<<1024, 256, 0, stream>>>(gAB, gABh, gAG, Mt, ws_f, out);
}